// Round 1
// baseline (313.639 us; speedup 1.0000x reference)
//
#include <hip/hip_runtime.h>

typedef _Float16 f16;
typedef _Float16 f16x8 __attribute__((ext_vector_type(8)));
typedef float f32x4 __attribute__((ext_vector_type(4)));

#define B_   4
#define C_   256
#define N_   4096
#define OUT_ 256

// ---------------------------------------------------------------------------
// Kernel A: transpose+convert x [B,C,N] f32 -> xt [B,N,C] f16, and W -> Wt[o][c] f16
// ---------------------------------------------------------------------------
__global__ __launch_bounds__(256) void k_prep(const float* __restrict__ x,
                                              const float* __restrict__ W,
                                              f16* __restrict__ xt,
                                              f16* __restrict__ Wt) {
    int bid = blockIdx.x;
    int t = threadIdx.x;
    if (bid < 1024) {
        // 64x64 tile transpose. 4 batches * 4 c-tiles * 64 n-tiles
        int b  = bid >> 8;
        int ct = (bid >> 6) & 3;
        int nt = bid & 63;
        int c0 = ct * 64, n0 = nt * 64;
        __shared__ float tile[64][65];
        int nl = t & 63;
        int r0 = t >> 6;
        #pragma unroll
        for (int i = 0; i < 16; ++i) {
            int cl = i * 4 + r0;
            tile[cl][nl] = x[((b * C_ + c0 + cl) * N_) + n0 + nl];
        }
        __syncthreads();
        #pragma unroll
        for (int i = 0; i < 16; ++i) {
            int nl2 = i * 4 + r0;
            int cl2 = nl;
            xt[((b * N_ + n0 + nl2) * C_) + c0 + cl2] = (f16)tile[cl2][nl2];
        }
    } else {
        // W[c][o] -> Wt[o][c], 65536 elems over 64 blocks
        int wb = bid - 1024;
        #pragma unroll
        for (int i = 0; i < 4; ++i) {
            int idx = wb * 1024 + i * 256 + t;
            int c = idx >> 8, o = idx & 255;
            Wt[o * C_ + c] = (f16)W[idx];
        }
    }
}

// ---------------------------------------------------------------------------
// Kernel B: support^T[b][o][m] = sum_c xt[b][m][c] * W[c][o]   (f16 out)
// grid: 4 b * 4 o-tiles * 64 m-tiles = 1024 blocks, 256 thr
// ---------------------------------------------------------------------------
__global__ __launch_bounds__(256) void k_support(const f16* __restrict__ xt,
                                                 const f16* __restrict__ Wt,
                                                 f16* __restrict__ supT) {
    int bid = blockIdx.x;
    int b  = bid >> 8;
    int ot = (bid >> 6) & 3;
    int mt = bid & 63;
    int o0 = ot * 64, m0 = mt * 64;
    __shared__ __align__(16) f16 Ws[64][264];
    __shared__ __align__(16) f16 Xs[64][264];
    int t = threadIdx.x;
    int wave = t >> 6, lane = t & 63, q = lane >> 4, l15 = lane & 15;
    #pragma unroll
    for (int p = 0; p < 8; ++p) {
        int idx = p * 256 + t;
        int row = idx >> 5, ch = (idx & 31) * 8;
        *(uint4*)&Ws[row][ch] = *(const uint4*)&Wt[(o0 + row) * C_ + ch];
        *(uint4*)&Xs[row][ch] = *(const uint4*)&xt[((b * N_) + m0 + row) * C_ + ch];
    }
    __syncthreads();
    f32x4 acc[4] = {};
    #pragma unroll
    for (int kk = 0; kk < 8; ++kk) {
        f16x8 a = *(f16x8*)&Ws[16 * wave + l15][kk * 32 + q * 8];
        #pragma unroll
        for (int ct = 0; ct < 4; ++ct) {
            f16x8 bb = *(f16x8*)&Xs[16 * ct + l15][kk * 32 + q * 8];
            acc[ct] = __builtin_amdgcn_mfma_f32_16x16x32_f16(a, bb, acc[ct], 0, 0, 0);
        }
    }
    // D[row=o][col=m]
    #pragma unroll
    for (int ct = 0; ct < 4; ++ct)
        #pragma unroll
        for (int r = 0; r < 4; ++r) {
            int og = o0 + 16 * wave + q * 4 + r;
            int mg = m0 + 16 * ct + l15;
            supT[((b * OUT_ + og) * N_) + mg] = (f16)acc[ct][r];
        }
}

// ---------------------------------------------------------------------------
// Kernel C: flash attention: out[b][o][n] = leaky( softmax_m(xt[n]·xt[m]) @ sup[m][o] )
// grid: 4 b * 64 n-tiles = 256 blocks, 256 thr (4 waves). BM=BN=64.
// ---------------------------------------------------------------------------
__global__ __launch_bounds__(256) void k_flash(const f16* __restrict__ xt,
                                               const f16* __restrict__ supT,
                                               float* __restrict__ out) {
    int bid = blockIdx.x;
    int b  = bid >> 6;
    int n0 = (bid & 63) * 64;
    __shared__ __align__(16) f16 Qs[64][264];
    __shared__ __align__(16) f16 Ks[64][264];
    __shared__ __align__(16) f16 Vt[256][72];
    __shared__ __align__(16) f16 Ps[64][72];
    int t = threadIdx.x;
    int wave = t >> 6, lane = t & 63, q = lane >> 4, l15 = lane & 15;

    #pragma unroll
    for (int p = 0; p < 8; ++p) {
        int idx = p * 256 + t;
        int row = idx >> 5, ch = (idx & 31) * 8;
        *(uint4*)&Qs[row][ch] = *(const uint4*)&xt[((b * N_) + n0 + row) * C_ + ch];
    }
    f32x4 oacc[16] = {};
    float m_run[4], l_run[4];
    #pragma unroll
    for (int r = 0; r < 4; ++r) { m_run[r] = -1e30f; l_run[r] = 0.f; }
    __syncthreads();

    for (int it = 0; it < 64; ++it) {
        int m0 = it * 64;
        // stage K (64x256) and V^T (256x64)
        #pragma unroll
        for (int p = 0; p < 8; ++p) {
            int idx = p * 256 + t;
            int row = idx >> 5, ch = (idx & 31) * 8;
            *(uint4*)&Ks[row][ch] = *(const uint4*)&xt[((b * N_) + m0 + row) * C_ + ch];
        }
        #pragma unroll
        for (int p = 0; p < 8; ++p) {
            int idx = p * 256 + t;
            int o = idx >> 3, j8 = (idx & 7) * 8;
            *(uint4*)&Vt[o][j8] = *(const uint4*)&supT[((b * OUT_ + o) * N_) + m0 + j8];
        }
        __syncthreads();
        // S = Q K^T  (64x64, K=256)
        f32x4 sacc[4] = {};
        #pragma unroll
        for (int kk = 0; kk < 8; ++kk) {
            f16x8 a = *(f16x8*)&Qs[16 * wave + l15][kk * 32 + q * 8];
            #pragma unroll
            for (int ct = 0; ct < 4; ++ct) {
                f16x8 bb = *(f16x8*)&Ks[16 * ct + l15][kk * 32 + q * 8];
                sacc[ct] = __builtin_amdgcn_mfma_f32_16x16x32_f16(a, bb, sacc[ct], 0, 0, 0);
            }
        }
        // online softmax, in-register (rows = 16*wave + q*4 + r, cols via lanes)
        float alpha[4];
        #pragma unroll
        for (int r = 0; r < 4; ++r) {
            float mx = fmaxf(fmaxf(sacc[0][r], sacc[1][r]), fmaxf(sacc[2][r], sacc[3][r]));
            mx = fmaxf(mx, __shfl_xor(mx, 1));
            mx = fmaxf(mx, __shfl_xor(mx, 2));
            mx = fmaxf(mx, __shfl_xor(mx, 4));
            mx = fmaxf(mx, __shfl_xor(mx, 8));
            float mnew = fmaxf(m_run[r], mx);
            alpha[r] = __expf(m_run[r] - mnew);
            m_run[r] = mnew;
            float p0 = __expf(sacc[0][r] - mnew);
            float p1 = __expf(sacc[1][r] - mnew);
            float p2 = __expf(sacc[2][r] - mnew);
            float p3 = __expf(sacc[3][r] - mnew);
            float sum = p0 + p1 + p2 + p3;
            sum += __shfl_xor(sum, 1);
            sum += __shfl_xor(sum, 2);
            sum += __shfl_xor(sum, 4);
            sum += __shfl_xor(sum, 8);
            l_run[r] = l_run[r] * alpha[r] + sum;
            int row = 16 * wave + q * 4 + r;
            Ps[row][0 * 16 + l15] = (f16)p0;
            Ps[row][1 * 16 + l15] = (f16)p1;
            Ps[row][2 * 16 + l15] = (f16)p2;
            Ps[row][3 * 16 + l15] = (f16)p3;
        }
        __syncthreads();
        // rescale O, then O += P V
        #pragma unroll
        for (int ct = 0; ct < 16; ++ct)
            #pragma unroll
            for (int r = 0; r < 4; ++r)
                oacc[ct][r] *= alpha[r];
        #pragma unroll
        for (int ks = 0; ks < 2; ++ks) {
            f16x8 a = *(f16x8*)&Ps[16 * wave + l15][ks * 32 + q * 8];
            #pragma unroll
            for (int ct = 0; ct < 16; ++ct) {
                f16x8 bb = *(f16x8*)&Vt[16 * ct + l15][ks * 32 + q * 8];
                oacc[ct] = __builtin_amdgcn_mfma_f32_16x16x32_f16(a, bb, oacc[ct], 0, 0, 0);
            }
        }
        __syncthreads();
    }
    // epilogue: /l, LeakyReLU, LDS-transpose, coalesced store to out[b][o][n]
    float invl[4];
    #pragma unroll
    for (int r = 0; r < 4; ++r) invl[r] = 1.0f / l_run[r];
    float(*Es)[65] = (float(*)[65]) & Ks[0][0];
    for (int cc = 0; cc < 4; ++cc) {
        #pragma unroll
        for (int j = 0; j < 4; ++j) {
            int ct = cc * 4 + j;
            #pragma unroll
            for (int r = 0; r < 4; ++r) {
                float v = oacc[ct][r] * invl[r];
                v = v >= 0.f ? v : 0.01f * v;
                Es[16 * wave + q * 4 + r][16 * j + l15] = v;
            }
        }
        __syncthreads();
        #pragma unroll
        for (int i = 0; i < 16; ++i) {
            int flat = i * 256 + t;
            int ol = flat >> 6, nl = flat & 63;
            out[((b * OUT_ + cc * 64 + ol) * N_) + n0 + nl] = Es[nl][ol];
        }
        __syncthreads();
    }
}

// ---------------------------------------------------------------------------
// Kernel D: per-channel mean / rstd over (B, N)
// ---------------------------------------------------------------------------
__global__ __launch_bounds__(256) void k_bnstats(const float* __restrict__ y,
                                                 float* __restrict__ stats) {
    int o = blockIdx.x;
    int t = threadIdx.x;
    float s = 0.f, ss = 0.f;
    for (int b = 0; b < B_; ++b) {
        const float* p = y + ((b * OUT_ + o) * N_);
        for (int i = t; i < N_; i += 256) {
            float v = p[i];
            s += v;
            ss += v * v;
        }
    }
    #pragma unroll
    for (int off = 32; off; off >>= 1) {
        s += __shfl_down(s, off);
        ss += __shfl_down(ss, off);
    }
    __shared__ float bs[4], bss[4];
    int wave = t >> 6, lane = t & 63;
    if (lane == 0) { bs[wave] = s; bss[wave] = ss; }
    __syncthreads();
    if (t == 0) {
        float S = bs[0] + bs[1] + bs[2] + bs[3];
        float SS = bss[0] + bss[1] + bss[2] + bss[3];
        float mean = S * (1.0f / 16384.0f);
        float var = SS * (1.0f / 16384.0f) - mean * mean;
        stats[o] = mean;
        stats[OUT_ + o] = rsqrtf(var + 1e-5f);
    }
}

// ---------------------------------------------------------------------------
// Kernel E: y = gamma*(y-mean)*rstd + beta  (in place, float4)
// ---------------------------------------------------------------------------
__global__ __launch_bounds__(256) void k_bnapply(float* __restrict__ y,
                                                 const float* __restrict__ stats,
                                                 const float* __restrict__ gamma,
                                                 const float* __restrict__ beta) {
    int idx = blockIdx.x * 256 + threadIdx.x;  // float4 index, 1M total
    int o = (idx >> 10) & 255;
    float rstd = stats[OUT_ + o];
    float g = gamma[o] * rstd;
    float bta = beta[o] - stats[o] * g;
    float4 v = ((const float4*)y)[idx];
    v.x = v.x * g + bta;
    v.y = v.y * g + bta;
    v.z = v.z * g + bta;
    v.w = v.w * g + bta;
    ((float4*)y)[idx] = v;
}

extern "C" void kernel_launch(void* const* d_in, const int* in_sizes, int n_in,
                              void* d_out, int out_size, void* d_ws, size_t ws_size,
                              hipStream_t stream) {
    const float* x     = (const float*)d_in[0];
    const float* W     = (const float*)d_in[1];
    const float* gamma = (const float*)d_in[2];
    const float* beta  = (const float*)d_in[3];
    float* out = (float*)d_out;

    f16* xt   = (f16*)d_ws;                       // 4*4096*256 f16 = 8 MB
    f16* supT = xt + (size_t)B_ * N_ * C_;        // 8 MB
    f16* Wt   = supT + (size_t)B_ * N_ * OUT_;    // 128 KB
    float* stats = (float*)(Wt + C_ * OUT_);      // 2 KB

    k_prep<<<1088, 256, 0, stream>>>(x, W, xt, Wt);
    k_support<<<1024, 256, 0, stream>>>(xt, Wt, supT);
    k_flash<<<256, 256, 0, stream>>>(xt, supT, out);
    k_bnstats<<<256, 256, 0, stream>>>(out, stats);
    k_bnapply<<<4096, 256, 0, stream>>>(out, stats, gamma, beta);
}

// Round 2
// 253.835 us; speedup vs baseline: 1.2356x; 1.2356x over previous
//
#include <hip/hip_runtime.h>

typedef _Float16 f16;
typedef _Float16 f16x8 __attribute__((ext_vector_type(8)));
typedef float f32x4 __attribute__((ext_vector_type(4)));

#define B_   4
#define C_   256
#define N_   4096
#define OUT_ 256

// ---------------------------------------------------------------------------
// Kernel A: transpose+convert x [B,C,N] f32 -> xt [B,N,C] f16, and W -> Wt[o][c] f16
// ---------------------------------------------------------------------------
__global__ __launch_bounds__(256) void k_prep(const float* __restrict__ x,
                                              const float* __restrict__ W,
                                              f16* __restrict__ xt,
                                              f16* __restrict__ Wt) {
    int bid = blockIdx.x;
    int t = threadIdx.x;
    if (bid < 1024) {
        int b  = bid >> 8;
        int ct = (bid >> 6) & 3;
        int nt = bid & 63;
        int c0 = ct * 64, n0 = nt * 64;
        __shared__ float tile[64][65];
        int nl = t & 63;
        int r0 = t >> 6;
        #pragma unroll
        for (int i = 0; i < 16; ++i) {
            int cl = i * 4 + r0;
            tile[cl][nl] = x[((b * C_ + c0 + cl) * N_) + n0 + nl];
        }
        __syncthreads();
        #pragma unroll
        for (int i = 0; i < 16; ++i) {
            int nl2 = i * 4 + r0;
            int cl2 = nl;
            xt[((b * N_ + n0 + nl2) * C_) + c0 + cl2] = (f16)tile[cl2][nl2];
        }
    } else {
        int wb = bid - 1024;
        #pragma unroll
        for (int i = 0; i < 4; ++i) {
            int idx = wb * 1024 + i * 256 + t;
            int c = idx >> 8, o = idx & 255;
            Wt[o * C_ + c] = (f16)W[idx];
        }
    }
}

// ---------------------------------------------------------------------------
// Kernel B: support^T[b][o][m] = sum_c xt[b][m][c] * W[c][o]   (f16 out)
// ---------------------------------------------------------------------------
__global__ __launch_bounds__(256) void k_support(const f16* __restrict__ xt,
                                                 const f16* __restrict__ Wt,
                                                 f16* __restrict__ supT) {
    int bid = blockIdx.x;
    int b  = bid >> 8;
    int ot = (bid >> 6) & 3;
    int mt = bid & 63;
    int o0 = ot * 64, m0 = mt * 64;
    __shared__ __align__(16) f16 Ws[64][264];
    __shared__ __align__(16) f16 Xs[64][264];
    int t = threadIdx.x;
    int wave = t >> 6, lane = t & 63, q = lane >> 4, l15 = lane & 15;
    #pragma unroll
    for (int p = 0; p < 8; ++p) {
        int idx = p * 256 + t;
        int row = idx >> 5, ch = (idx & 31) * 8;
        *(uint4*)&Ws[row][ch] = *(const uint4*)&Wt[(o0 + row) * C_ + ch];
        *(uint4*)&Xs[row][ch] = *(const uint4*)&xt[((b * N_) + m0 + row) * C_ + ch];
    }
    __syncthreads();
    f32x4 acc[4] = {};
    #pragma unroll
    for (int kk = 0; kk < 8; ++kk) {
        f16x8 a = *(f16x8*)&Ws[16 * wave + l15][kk * 32 + q * 8];
        #pragma unroll
        for (int ct = 0; ct < 4; ++ct) {
            f16x8 bb = *(f16x8*)&Xs[16 * ct + l15][kk * 32 + q * 8];
            acc[ct] = __builtin_amdgcn_mfma_f32_16x16x32_f16(a, bb, acc[ct], 0, 0, 0);
        }
    }
    #pragma unroll
    for (int ct = 0; ct < 4; ++ct)
        #pragma unroll
        for (int r = 0; r < 4; ++r) {
            int og = o0 + 16 * wave + q * 4 + r;
            int mg = m0 + 16 * ct + l15;
            supT[((b * OUT_ + og) * N_) + mg] = (f16)acc[ct][r];
        }
}

// ---------------------------------------------------------------------------
// Kernel C: split-K flash. 512 blocks: (half h, batch b, n-tile nb).
// Each block: Q-tile 64 rows, m-range [h*2048, h*2048+2048), 32 iters of BN=64.
// Q fragments in registers (no Qs LDS). PV: waves split OUT into 64-wide slabs.
// Stores l-normalized partial O (f16) + per-row m,l.
// ---------------------------------------------------------------------------
__global__ __launch_bounds__(256, 2) void k_flash(const f16* __restrict__ xt,
                                                  const f16* __restrict__ supT,
                                                  f16* __restrict__ Op,
                                                  float* __restrict__ Ml) {
    int bid = blockIdx.x;
    int h  = bid >> 8;
    int b  = (bid >> 6) & 3;
    int n0 = (bid & 63) * 64;

    __shared__ __align__(16) f16 Ks[64][264];   // 33792 B
    __shared__ __align__(16) f16 Vt[256][72];   // 36864 B
    __shared__ __align__(16) f16 Ps[64][72];    //  9216 B
    __shared__ __align__(16) float Al[64];      //   256 B   (total 80128 -> 2 blocks/CU)

    int t = threadIdx.x;
    int wave = t >> 6, lane = t & 63, q = lane >> 4, l15 = lane & 15;

    // Q fragments: rows 16*wave + l15, all 256 channels -> 8 f16x8 (32 VGPRs)
    const f16* qbase = xt + ((size_t)(b * N_) + n0 + 16 * wave + l15) * C_;
    f16x8 qf[8];
    #pragma unroll
    for (int kk = 0; kk < 8; ++kk)
        qf[kk] = *(const f16x8*)&qbase[kk * 32 + q * 8];

    f32x4 oacc[4][4] = {};
    float m_run[4], l_run[4];
    #pragma unroll
    for (int r = 0; r < 4; ++r) { m_run[r] = -1e30f; l_run[r] = 0.f; }

    for (int it = 0; it < 32; ++it) {
        int m0 = (h * 32 + it) * 64;
        // stage K (64 x 256) and V^T (256 x 64)
        #pragma unroll
        for (int p = 0; p < 8; ++p) {
            int idx = p * 256 + t;
            int row = idx >> 5, ch = (idx & 31) * 8;
            *(uint4*)&Ks[row][ch] = *(const uint4*)&xt[((b * N_) + m0 + row) * C_ + ch];
        }
        #pragma unroll
        for (int p = 0; p < 8; ++p) {
            int idx = p * 256 + t;
            int o = idx >> 3, j8 = (idx & 7) * 8;
            *(uint4*)&Vt[o][j8] = *(const uint4*)&supT[((b * OUT_ + o) * N_) + m0 + j8];
        }
        __syncthreads();

        // S = Q K^T (64x64, K=256); wave owns rows 16*wave..+15
        f32x4 sacc[4] = {};
        #pragma unroll
        for (int kk = 0; kk < 8; ++kk) {
            #pragma unroll
            for (int ct = 0; ct < 4; ++ct) {
                f16x8 bb = *(f16x8*)&Ks[16 * ct + l15][kk * 32 + q * 8];
                sacc[ct] = __builtin_amdgcn_mfma_f32_16x16x32_f16(qf[kk], bb, sacc[ct], 0, 0, 0);
            }
        }
        // online softmax on own rows; publish P (f16) and alpha
        float alpha[4];
        #pragma unroll
        for (int r = 0; r < 4; ++r) {
            float mx = fmaxf(fmaxf(sacc[0][r], sacc[1][r]), fmaxf(sacc[2][r], sacc[3][r]));
            mx = fmaxf(mx, __shfl_xor(mx, 1));
            mx = fmaxf(mx, __shfl_xor(mx, 2));
            mx = fmaxf(mx, __shfl_xor(mx, 4));
            mx = fmaxf(mx, __shfl_xor(mx, 8));
            float mnew = fmaxf(m_run[r], mx);
            alpha[r] = __expf(m_run[r] - mnew);
            m_run[r] = mnew;
            float p0 = __expf(sacc[0][r] - mnew);
            float p1 = __expf(sacc[1][r] - mnew);
            float p2 = __expf(sacc[2][r] - mnew);
            float p3 = __expf(sacc[3][r] - mnew);
            float sum = p0 + p1 + p2 + p3;
            sum += __shfl_xor(sum, 1);
            sum += __shfl_xor(sum, 2);
            sum += __shfl_xor(sum, 4);
            sum += __shfl_xor(sum, 8);
            l_run[r] = l_run[r] * alpha[r] + sum;
            int row = 16 * wave + q * 4 + r;
            Ps[row][0 * 16 + l15] = (f16)p0;
            Ps[row][1 * 16 + l15] = (f16)p1;
            Ps[row][2 * 16 + l15] = (f16)p2;
            Ps[row][3 * 16 + l15] = (f16)p3;
            if (l15 == 0) Al[row] = alpha[r];
        }
        __syncthreads();

        // rescale O by alpha (broadcast via LDS), then O += P V
        // wave computes O[all 64 n][o-slab 64*wave .. +64)
        float4 av[4];
        #pragma unroll
        for (int nt = 0; nt < 4; ++nt)
            av[nt] = *(const float4*)&Al[16 * nt + 4 * q];
        #pragma unroll
        for (int nt = 0; nt < 4; ++nt)
            #pragma unroll
            for (int ot = 0; ot < 4; ++ot)
                #pragma unroll
                for (int r = 0; r < 4; ++r)
                    oacc[nt][ot][r] *= ((const float*)&av[nt])[r];
        #pragma unroll
        for (int ks = 0; ks < 2; ++ks) {
            f16x8 af[4], bf[4];
            #pragma unroll
            for (int nt = 0; nt < 4; ++nt)
                af[nt] = *(f16x8*)&Ps[16 * nt + l15][ks * 32 + q * 8];
            #pragma unroll
            for (int ot = 0; ot < 4; ++ot)
                bf[ot] = *(f16x8*)&Vt[64 * wave + 16 * ot + l15][ks * 32 + q * 8];
            #pragma unroll
            for (int nt = 0; nt < 4; ++nt)
                #pragma unroll
                for (int ot = 0; ot < 4; ++ot)
                    oacc[nt][ot] = __builtin_amdgcn_mfma_f32_16x16x32_f16(af[nt], bf[ot], oacc[nt][ot], 0, 0, 0);
        }
        __syncthreads();
    }

    // broadcast 1/l for all rows, store normalized f16 partials + (m,l)
    if (l15 == 0) {
        #pragma unroll
        for (int r = 0; r < 4; ++r)
            Al[16 * wave + q * 4 + r] = 1.0f / l_run[r];
    }
    __syncthreads();
    float4 lv[4];
    #pragma unroll
    for (int nt = 0; nt < 4; ++nt)
        lv[nt] = *(const float4*)&Al[16 * nt + 4 * q];

    f16* Obase = Op + (size_t)bid * (64 * 256);
    #pragma unroll
    for (int nt = 0; nt < 4; ++nt)
        #pragma unroll
        for (int ot = 0; ot < 4; ++ot)
            #pragma unroll
            for (int r = 0; r < 4; ++r) {
                int n = 16 * nt + q * 4 + r;
                int o = 64 * wave + 16 * ot + l15;
                Obase[n * 256 + o] = (f16)(oacc[nt][ot][r] * ((const float*)&lv[nt])[r]);
            }
    float* Mlb = Ml + (size_t)bid * 128;
    if (l15 == 0) {
        #pragma unroll
        for (int r = 0; r < 4; ++r) {
            Mlb[16 * wave + q * 4 + r] = m_run[r];
            Mlb[64 + 16 * wave + q * 4 + r] = l_run[r];
        }
    }
}

// ---------------------------------------------------------------------------
// Kernel C2: merge the two split-K halves + LeakyReLU + transpose store.
// grid 256 = (b, nb); thread t owns output channel o = t.
// ---------------------------------------------------------------------------
__global__ __launch_bounds__(256) void k_merge(const f16* __restrict__ Op,
                                               const float* __restrict__ Ml,
                                               float* __restrict__ out) {
    int bid = blockIdx.x;
    int b  = bid >> 6;
    int n0 = (bid & 63) * 64;
    int t = threadIdx.x;
    const f16* O1 = Op + (size_t)bid * (64 * 256);
    const f16* O2 = Op + (size_t)(bid + 256) * (64 * 256);
    const float* Ml1 = Ml + (size_t)bid * 128;
    const float* Ml2 = Ml + (size_t)(bid + 256) * 128;
    __shared__ float c1s[64], c2s[64];
    if (t < 64) {
        float m1 = Ml1[t], l1 = Ml1[64 + t];
        float m2 = Ml2[t], l2 = Ml2[64 + t];
        float m = fmaxf(m1, m2);
        float w1 = __expf(m1 - m) * l1;
        float w2 = __expf(m2 - m) * l2;
        float inv = 1.0f / (w1 + w2);
        c1s[t] = w1 * inv;
        c2s[t] = w2 * inv;
    }
    __syncthreads();
    float vv[64];
    #pragma unroll
    for (int n = 0; n < 64; ++n) {
        float v = c1s[n] * (float)O1[n * 256 + t] + c2s[n] * (float)O2[n * 256 + t];
        vv[n] = v >= 0.f ? v : 0.01f * v;
    }
    float* dst = out + ((size_t)(b * OUT_ + t)) * N_ + n0;
    #pragma unroll
    for (int c = 0; c < 16; ++c) {
        float4 w = { vv[4 * c], vv[4 * c + 1], vv[4 * c + 2], vv[4 * c + 3] };
        *(float4*)&dst[4 * c] = w;
    }
}

// ---------------------------------------------------------------------------
// Kernel D: per-channel mean / rstd over (B, N)
// ---------------------------------------------------------------------------
__global__ __launch_bounds__(256) void k_bnstats(const float* __restrict__ y,
                                                 float* __restrict__ stats) {
    int o = blockIdx.x;
    int t = threadIdx.x;
    float s = 0.f, ss = 0.f;
    for (int b = 0; b < B_; ++b) {
        const float* p = y + ((b * OUT_ + o) * N_);
        for (int i = t; i < N_; i += 256) {
            float v = p[i];
            s += v;
            ss += v * v;
        }
    }
    #pragma unroll
    for (int off = 32; off; off >>= 1) {
        s += __shfl_down(s, off);
        ss += __shfl_down(ss, off);
    }
    __shared__ float bs[4], bss[4];
    int wave = t >> 6, lane = t & 63;
    if (lane == 0) { bs[wave] = s; bss[wave] = ss; }
    __syncthreads();
    if (t == 0) {
        float S = bs[0] + bs[1] + bs[2] + bs[3];
        float SS = bss[0] + bss[1] + bss[2] + bss[3];
        float mean = S * (1.0f / 16384.0f);
        float var = SS * (1.0f / 16384.0f) - mean * mean;
        stats[o] = mean;
        stats[OUT_ + o] = rsqrtf(var + 1e-5f);
    }
}

// ---------------------------------------------------------------------------
// Kernel E: y = gamma*(y-mean)*rstd + beta  (in place, float4)
// ---------------------------------------------------------------------------
__global__ __launch_bounds__(256) void k_bnapply(float* __restrict__ y,
                                                 const float* __restrict__ stats,
                                                 const float* __restrict__ gamma,
                                                 const float* __restrict__ beta) {
    int idx = blockIdx.x * 256 + threadIdx.x;
    int o = (idx >> 10) & 255;
    float rstd = stats[OUT_ + o];
    float g = gamma[o] * rstd;
    float bta = beta[o] - stats[o] * g;
    float4 v = ((const float4*)y)[idx];
    v.x = v.x * g + bta;
    v.y = v.y * g + bta;
    v.z = v.z * g + bta;
    v.w = v.w * g + bta;
    ((float4*)y)[idx] = v;
}

extern "C" void kernel_launch(void* const* d_in, const int* in_sizes, int n_in,
                              void* d_out, int out_size, void* d_ws, size_t ws_size,
                              hipStream_t stream) {
    const float* x     = (const float*)d_in[0];
    const float* W     = (const float*)d_in[1];
    const float* gamma = (const float*)d_in[2];
    const float* beta  = (const float*)d_in[3];
    float* out = (float*)d_out;

    f16* xt    = (f16*)d_ws;                      // 8 MB
    f16* supT  = xt + (size_t)B_ * N_ * C_;       // 8 MB
    f16* Wt    = supT + (size_t)B_ * N_ * OUT_;   // 128 KB
    f16* Op    = Wt + C_ * OUT_;                  // 2*256*16384 f16 = 16 MB
    float* Ml  = (float*)(Op + (size_t)2 * 256 * 64 * 256);  // 256 KB
    float* stats = Ml + 512 * 128;                // 2 KB

    k_prep<<<1088, 256, 0, stream>>>(x, W, xt, Wt);
    k_support<<<1024, 256, 0, stream>>>(xt, Wt, supT);
    k_flash<<<512, 256, 0, stream>>>(xt, supT, Op, Ml);
    k_merge<<<256, 256, 0, stream>>>(Op, Ml, out);
    k_bnstats<<<256, 256, 0, stream>>>(out, stats);
    k_bnapply<<<4096, 256, 0, stream>>>(out, stats, gamma, beta);
}